// Round 1
// baseline (232.960 us; speedup 1.0000x reference)
//
#include <hip/hip_runtime.h>

#define DIM   256
#define HALF  128
#define F0    10
#define F1    25
#define BROWS 1024
#define M1    10240   // BROWS * F0

#define PAD   260     // 256 + 4: keeps float4 alignment (260*4 = 1040 B, 16B multiple)

// ---------------- Kernel 1: n1 = aggregate(h1, h2 groups, W0s, W0n, ReLU) ----------------
// 16 rows per block, 256 threads. Output n1 [M1][256] fp32 into workspace.
#define R1 16

__global__ __launch_bounds__(256) void sage_layer0_hop1(
    const float* __restrict__ feat,
    const int*   __restrict__ sn1,
    const int*   __restrict__ sn2,
    const float* __restrict__ Ws,
    const float* __restrict__ Wn,
    float*       __restrict__ n1)
{
    __shared__ float sh_self[R1][PAD];
    __shared__ float sh_agg [R1][PAD];
    __shared__ int   s_idx [R1];
    __shared__ int   s_nidx[R1 * F1];   // 400

    const int tid     = threadIdx.x;
    const int rowbase = blockIdx.x * R1;

    if (tid < R1) s_idx[tid] = sn1[rowbase + tid];
    for (int t = tid; t < R1 * F1; t += 256) s_nidx[t] = sn2[rowbase * F1 + t];
    __syncthreads();

    // ---- phase 1: gather + mean. wave w loads rows 4w..4w+3; lane covers 4 dims (float4).
    const int wave = tid >> 6;
    const int lane = tid & 63;
    for (int rr = 0; rr < 4; ++rr) {
        const int r = wave * 4 + rr;
        const float4 sv = *(const float4*)(feat + (size_t)s_idx[r] * DIM + lane * 4);
        *(float4*)(&sh_self[r][lane * 4]) = sv;

        float4 a = make_float4(0.f, 0.f, 0.f, 0.f);
        #pragma unroll
        for (int j = 0; j < F1; ++j) {
            const float4 v = *(const float4*)(feat + (size_t)s_nidx[r * F1 + j] * DIM + lane * 4);
            a.x += v.x; a.y += v.y; a.z += v.z; a.w += v.w;
        }
        const float sc = 1.0f / (float)F1;
        a.x *= sc; a.y *= sc; a.z *= sc; a.w *= sc;
        *(float4*)(&sh_agg[r][lane * 4]) = a;
    }
    __syncthreads();

    // ---- phase 2: dual GEMM. thread -> 2 adjacent cols x 8 rows. Wave-uniform halves.
    const int  u     = tid & 127;      // col-pair id (0..127)
    const int  c0    = u * 2;          // output col (0..254, even)
    const int  rb    = (tid >> 7) * 8; // rows 0-7 or 8-15
    const bool neigh = (c0 >= HALF);
    const float* __restrict__ W = neigh ? Wn : Ws;
    const int  col   = neigh ? (c0 - HALF) : c0;
    const float (*src)[PAD] = neigh ? sh_agg : sh_self;

    float acc0[8], acc1[8];
    #pragma unroll
    for (int r = 0; r < 8; ++r) { acc0[r] = 0.f; acc1[r] = 0.f; }

    for (int d = 0; d < DIM; d += 4) {
        const float2 w0 = *(const float2*)(W + (d + 0) * HALF + col);
        const float2 w1 = *(const float2*)(W + (d + 1) * HALF + col);
        const float2 w2 = *(const float2*)(W + (d + 2) * HALF + col);
        const float2 w3 = *(const float2*)(W + (d + 3) * HALF + col);
        #pragma unroll
        for (int r = 0; r < 8; ++r) {
            const float4 h = *(const float4*)(&src[rb + r][d]);  // broadcast read
            acc0[r] += h.x * w0.x + h.y * w1.x + h.z * w2.x + h.w * w3.x;
            acc1[r] += h.x * w0.y + h.y * w1.y + h.z * w2.y + h.w * w3.y;
        }
    }

    #pragma unroll
    for (int r = 0; r < 8; ++r) {
        float2 o;
        o.x = fmaxf(acc0[r], 0.f);
        o.y = fmaxf(acc1[r], 0.f);
        *(float2*)(n1 + (size_t)(rowbase + rb + r) * DIM + c0) = o;
    }
}

// ---------------- Kernel 2: n0 = aggregate(h0, h1 groups, W0, ReLU);
//                  out = aggregate(n0, n1 groups, W1, no act). 4 rows/block. ----------------
#define R2 4

__global__ __launch_bounds__(256) void sage_final(
    const float* __restrict__ feat,
    const int*   __restrict__ sn0,
    const int*   __restrict__ sn1,
    const float* __restrict__ W0s,
    const float* __restrict__ W0n,
    const float* __restrict__ W1s,
    const float* __restrict__ W1n,
    const float* __restrict__ n1,
    float*       __restrict__ out)
{
    __shared__ float sh_self[R2][PAD];
    __shared__ float sh_agg [R2][PAD];
    __shared__ float sh_n0  [R2][PAD];
    __shared__ float sh_aggn[R2][PAD];
    __shared__ int   s_idx [R2];
    __shared__ int   s_nidx[R2 * F0];   // 40

    const int tid     = threadIdx.x;
    const int rowbase = blockIdx.x * R2;

    if (tid < R2)      s_idx[tid]  = sn0[rowbase + tid];
    if (tid < R2 * F0) s_nidx[tid] = sn1[rowbase * F0 + tid];
    __syncthreads();

    // ---- phase A: gather h0, mean(10) of features, mean(10) of n1 rows.
    const int wave = tid >> 6;   // wave w -> row w
    const int lane = tid & 63;
    {
        const int r = wave;
        const float4 sv = *(const float4*)(feat + (size_t)s_idx[r] * DIM + lane * 4);
        *(float4*)(&sh_self[r][lane * 4]) = sv;

        float4 a  = make_float4(0.f, 0.f, 0.f, 0.f);
        float4 an = make_float4(0.f, 0.f, 0.f, 0.f);
        #pragma unroll
        for (int j = 0; j < F0; ++j) {
            const int gi = s_nidx[r * F0 + j];
            const float4 v  = *(const float4*)(feat + (size_t)gi * DIM + lane * 4);
            a.x += v.x; a.y += v.y; a.z += v.z; a.w += v.w;
            const float4 vn = *(const float4*)(n1 + (size_t)((rowbase + r) * F0 + j) * DIM + lane * 4);
            an.x += vn.x; an.y += vn.y; an.z += vn.z; an.w += vn.w;
        }
        const float sc = 1.0f / (float)F0;
        a.x  *= sc; a.y  *= sc; a.z  *= sc; a.w  *= sc;
        an.x *= sc; an.y *= sc; an.z *= sc; an.w *= sc;
        *(float4*)(&sh_agg [r][lane * 4]) = a;
        *(float4*)(&sh_aggn[r][lane * 4]) = an;
    }
    __syncthreads();

    const int  u     = tid & 127;
    const int  c0    = u * 2;
    const int  rb    = (tid >> 7) * 2;  // rows 0-1 or 2-3
    const bool neigh = (c0 >= HALF);
    const int  col   = neigh ? (c0 - HALF) : c0;

    // ---- phase B: n0 (layer 0, ReLU) -> LDS
    {
        const float* __restrict__ W = neigh ? W0n : W0s;
        const float (*src)[PAD] = neigh ? sh_agg : sh_self;
        float a0[2] = {0.f, 0.f}, a1[2] = {0.f, 0.f};
        for (int d = 0; d < DIM; d += 4) {
            const float2 w0 = *(const float2*)(W + (d + 0) * HALF + col);
            const float2 w1 = *(const float2*)(W + (d + 1) * HALF + col);
            const float2 w2 = *(const float2*)(W + (d + 2) * HALF + col);
            const float2 w3 = *(const float2*)(W + (d + 3) * HALF + col);
            #pragma unroll
            for (int r = 0; r < 2; ++r) {
                const float4 h = *(const float4*)(&src[rb + r][d]);
                a0[r] += h.x * w0.x + h.y * w1.x + h.z * w2.x + h.w * w3.x;
                a1[r] += h.x * w0.y + h.y * w1.y + h.z * w2.y + h.w * w3.y;
            }
        }
        #pragma unroll
        for (int r = 0; r < 2; ++r) {
            float2 o;
            o.x = fmaxf(a0[r], 0.f);
            o.y = fmaxf(a1[r], 0.f);
            *(float2*)(&sh_n0[rb + r][c0]) = o;
        }
    }
    __syncthreads();

    // ---- phase C: final layer (no activation) -> out
    {
        const float* __restrict__ W = neigh ? W1n : W1s;
        const float (*src)[PAD] = neigh ? sh_aggn : sh_n0;
        float a0[2] = {0.f, 0.f}, a1[2] = {0.f, 0.f};
        for (int d = 0; d < DIM; d += 4) {
            const float2 w0 = *(const float2*)(W + (d + 0) * HALF + col);
            const float2 w1 = *(const float2*)(W + (d + 1) * HALF + col);
            const float2 w2 = *(const float2*)(W + (d + 2) * HALF + col);
            const float2 w3 = *(const float2*)(W + (d + 3) * HALF + col);
            #pragma unroll
            for (int r = 0; r < 2; ++r) {
                const float4 h = *(const float4*)(&src[rb + r][d]);
                a0[r] += h.x * w0.x + h.y * w1.x + h.z * w2.x + h.w * w3.x;
                a1[r] += h.x * w0.y + h.y * w1.y + h.z * w2.y + h.w * w3.y;
            }
        }
        #pragma unroll
        for (int r = 0; r < 2; ++r) {
            float2 o;
            o.x = a0[r];
            o.y = a1[r];
            *(float2*)(out + (size_t)(rowbase + rb + r) * DIM + c0) = o;
        }
    }
}

extern "C" void kernel_launch(void* const* d_in, const int* in_sizes, int n_in,
                              void* d_out, int out_size, void* d_ws, size_t ws_size,
                              hipStream_t stream) {
    (void)in_sizes; (void)n_in; (void)out_size; (void)ws_size;
    const float* feat = (const float*)d_in[0];
    const int*   sn0  = (const int*)  d_in[1];
    const int*   sn1  = (const int*)  d_in[2];
    const int*   sn2  = (const int*)  d_in[3];
    const float* W0s  = (const float*)d_in[4];
    const float* W0n  = (const float*)d_in[5];
    const float* W1s  = (const float*)d_in[6];
    const float* W1n  = (const float*)d_in[7];
    float* out = (float*)d_out;
    float* n1  = (float*)d_ws;   // 10240*256*4 = 10.49 MB

    sage_layer0_hop1<<<M1 / R1, 256, 0, stream>>>(feat, sn1, sn2, W0s, W0n, n1);
    sage_final<<<BROWS / R2, 256, 0, stream>>>(feat, sn0, sn1, W0s, W0n, W1s, W1n, n1, out);
}

// Round 2
// 227.668 us; speedup vs baseline: 1.0232x; 1.0232x over previous
//
#include <hip/hip_runtime.h>

#define DIM   256
#define HALF  128
#define F0    10
#define F1    25
#define B0    1024
#define M1    10240   // B0 * F0

#define PAD   260     // 256 + 4 floats: float4-aligned row stride
#define R     8       // rows per block in layer-0 kernel

// ---------------- Kernel 1: layer-0 for BOTH hops.
// Blocks [0, 128): hop 0   (self=sn0, neigh=sn1, fanout 10) -> n0 (= d_out scratch)
// Blocks [128,1408): hop 1 (self=sn1, neigh=sn2, fanout 25) -> n1 (= d_ws)
__global__ __launch_bounds__(256) void sage_layer0(
    const float* __restrict__ feat,
    const int*   __restrict__ sn0,
    const int*   __restrict__ sn1,
    const int*   __restrict__ sn2,
    const float* __restrict__ Ws,
    const float* __restrict__ Wn,
    float*       __restrict__ n0,
    float*       __restrict__ n1)
{
    __shared__ float sh_self[R][PAD];
    __shared__ float sh_agg [R][PAD];
    __shared__ int   s_idx [R];
    __shared__ int   s_nidx[R * F1];   // 200 max

    const int tid = threadIdx.x;
    int gb = blockIdx.x;

    const int* selfIdx; const int* neighIdx; float* dst; int nf; float sc;
    if (gb < B0 / R) {
        selfIdx = sn0; neighIdx = sn1; dst = n0; nf = F0; sc = 1.0f / F0;
    } else {
        gb -= B0 / R;
        selfIdx = sn1; neighIdx = sn2; dst = n1; nf = F1; sc = 1.0f / F1;
    }
    const int rowbase = gb * R;

    if (tid < R) s_idx[tid] = selfIdx[rowbase + tid];
    for (int t = tid; t < R * nf; t += 256) s_nidx[t] = neighIdx[rowbase * nf + t];
    __syncthreads();

    // ---- phase 1: gather + mean. wave w handles rows 2w, 2w+1; lane covers 4 dims.
    const int wave = tid >> 6;
    const int lane = tid & 63;
    for (int rr = 0; rr < 2; ++rr) {
        const int r = wave * 2 + rr;
        *(float4*)(&sh_self[r][lane * 4]) =
            *(const float4*)(feat + (size_t)s_idx[r] * DIM + lane * 4);

        float4 a = make_float4(0.f, 0.f, 0.f, 0.f);
        #pragma unroll 5
        for (int j = 0; j < nf; ++j) {
            const float4 v = *(const float4*)(feat + (size_t)s_nidx[r * nf + j] * DIM + lane * 4);
            a.x += v.x; a.y += v.y; a.z += v.z; a.w += v.w;
        }
        a.x *= sc; a.y *= sc; a.z *= sc; a.w *= sc;
        *(float4*)(&sh_agg[r][lane * 4]) = a;
    }
    __syncthreads();

    // ---- phase 2: dual GEMM + ReLU. thread -> 2 adjacent cols x 4 rows.
    const int  u     = tid & 127;
    const int  c0    = u * 2;
    const int  rb    = (tid >> 7) * 4;   // rows 0-3 or 4-7
    const bool neigh = (c0 >= HALF);
    const float* __restrict__ W = neigh ? Wn : Ws;
    const int  col   = neigh ? (c0 - HALF) : c0;
    const float (*src)[PAD] = neigh ? sh_agg : sh_self;

    float acc0[4] = {0.f, 0.f, 0.f, 0.f};
    float acc1[4] = {0.f, 0.f, 0.f, 0.f};

    for (int d = 0; d < DIM; d += 4) {
        const float2 w0 = *(const float2*)(W + (d + 0) * HALF + col);
        const float2 w1 = *(const float2*)(W + (d + 1) * HALF + col);
        const float2 w2 = *(const float2*)(W + (d + 2) * HALF + col);
        const float2 w3 = *(const float2*)(W + (d + 3) * HALF + col);
        #pragma unroll
        for (int r = 0; r < 4; ++r) {
            const float4 h = *(const float4*)(&src[rb + r][d]);  // LDS broadcast
            acc0[r] += h.x * w0.x + h.y * w1.x + h.z * w2.x + h.w * w3.x;
            acc1[r] += h.x * w0.y + h.y * w1.y + h.z * w2.y + h.w * w3.y;
        }
    }

    #pragma unroll
    for (int r = 0; r < 4; ++r) {
        float2 o;
        o.x = fmaxf(acc0[r], 0.f);
        o.y = fmaxf(acc1[r], 0.f);
        *(float2*)(dst + (size_t)(rowbase + rb + r) * DIM + c0) = o;
    }
}

// ---------------- Kernel 2: final layer. out = concat(n0 @ W1s, mean10(n1) @ W1n).
// n0 lives in the out buffer (read rows == written rows, read-before-write per block).
#define R2 4

__global__ __launch_bounds__(256) void sage_final(
    const float* __restrict__ n1,
    const float* __restrict__ W1s,
    const float* __restrict__ W1n,
    float*       out)              // aliases n0 input — no restrict
{
    __shared__ float sh_n0 [R2][PAD];
    __shared__ float sh_agg[R2][PAD];

    const int tid     = threadIdx.x;
    const int rowbase = blockIdx.x * R2;
    const int wave    = tid >> 6;   // wave w -> row w
    const int lane    = tid & 63;

    // ---- phase A: load n0 row; mean of 10 CONSECUTIVE n1 rows (coalesced stream).
    {
        const int r = wave;
        *(float4*)(&sh_n0[r][lane * 4]) =
            *(const float4*)(out + (size_t)(rowbase + r) * DIM + lane * 4);

        const float* base = n1 + (size_t)(rowbase + r) * F0 * DIM + lane * 4;
        float4 a = make_float4(0.f, 0.f, 0.f, 0.f);
        #pragma unroll
        for (int j = 0; j < F0; ++j) {
            const float4 v = *(const float4*)(base + (size_t)j * DIM);
            a.x += v.x; a.y += v.y; a.z += v.z; a.w += v.w;
        }
        const float sc = 1.0f / (float)F0;
        a.x *= sc; a.y *= sc; a.z *= sc; a.w *= sc;
        *(float4*)(&sh_agg[r][lane * 4]) = a;
    }
    __syncthreads();

    // ---- phase B: final GEMM, no activation. thread -> 2 cols x 2 rows.
    const int  u     = tid & 127;
    const int  c0    = u * 2;
    const int  rb    = (tid >> 7) * 2;
    const bool neigh = (c0 >= HALF);
    const float* __restrict__ W = neigh ? W1n : W1s;
    const int  col   = neigh ? (c0 - HALF) : c0;
    const float (*src)[PAD] = neigh ? sh_agg : sh_n0;

    float a0[2] = {0.f, 0.f}, a1[2] = {0.f, 0.f};
    for (int d = 0; d < DIM; d += 4) {
        const float2 w0 = *(const float2*)(W + (d + 0) * HALF + col);
        const float2 w1 = *(const float2*)(W + (d + 1) * HALF + col);
        const float2 w2 = *(const float2*)(W + (d + 2) * HALF + col);
        const float2 w3 = *(const float2*)(W + (d + 3) * HALF + col);
        #pragma unroll
        for (int r = 0; r < 2; ++r) {
            const float4 h = *(const float4*)(&src[rb + r][d]);
            a0[r] += h.x * w0.x + h.y * w1.x + h.z * w2.x + h.w * w3.x;
            a1[r] += h.x * w0.y + h.y * w1.y + h.z * w2.y + h.w * w3.y;
        }
    }

    #pragma unroll
    for (int r = 0; r < 2; ++r) {
        float2 o;
        o.x = a0[r];
        o.y = a1[r];
        *(float2*)(out + (size_t)(rowbase + rb + r) * DIM + c0) = o;
    }
}

extern "C" void kernel_launch(void* const* d_in, const int* in_sizes, int n_in,
                              void* d_out, int out_size, void* d_ws, size_t ws_size,
                              hipStream_t stream) {
    (void)in_sizes; (void)n_in; (void)out_size; (void)ws_size;
    const float* feat = (const float*)d_in[0];
    const int*   sn0  = (const int*)  d_in[1];
    const int*   sn1  = (const int*)  d_in[2];
    const int*   sn2  = (const int*)  d_in[3];
    const float* W0s  = (const float*)d_in[4];
    const float* W0n  = (const float*)d_in[5];
    const float* W1s  = (const float*)d_in[6];
    const float* W1n  = (const float*)d_in[7];
    float* out = (float*)d_out;
    float* n1  = (float*)d_ws;   // 10240*256*4 = 10.49 MB

    // n0 (1024x256) is staged in the out buffer, then overwritten by sage_final.
    sage_layer0<<<(B0 + M1) / R, 256, 0, stream>>>(feat, sn0, sn1, sn2, W0s, W0n, out, n1);
    sage_final <<<B0 / R2, 256, 0, stream>>>(n1, W1s, W1n, out);
}

// Round 3
// 227.558 us; speedup vs baseline: 1.0237x; 1.0005x over previous
//
#include <hip/hip_runtime.h>

#define DIM   256
#define HALF  128
#define F0    10
#define F1    25
#define B0    1024
#define M1    10240   // B0 * F0

#define PAD   260     // 256 + 4 floats: float4-aligned row stride
#define R     8       // rows per block in layer-0 kernel

// Per-hop specialized body: compile-time fanout -> full unroll -> ~52 gather
// loads in flight per wave (round 1 showed MLP-per-wave dominates occupancy).
template<int NF>
__device__ __forceinline__ void layer0_gather(
    const float* __restrict__ feat,
    const int*   __restrict__ selfIdx,
    const int*   __restrict__ neighIdx,
    int rowbase,
    float (*sh_self)[PAD], float (*sh_agg)[PAD])
{
    const int tid  = threadIdx.x;
    const int wv   = __builtin_amdgcn_readfirstlane(tid >> 6);  // wave-uniform
    const int lane = tid & 63;
    const float sc = 1.0f / (float)NF;

    #pragma unroll
    for (int rr = 0; rr < 2; ++rr) {
        const int r  = wv * 2 + rr;
        const int si = selfIdx[rowbase + r];                    // scalar load
        *(float4*)(&sh_self[r][lane * 4]) =
            *(const float4*)(feat + (size_t)si * DIM + lane * 4);

        float4 a = make_float4(0.f, 0.f, 0.f, 0.f);
        #pragma unroll
        for (int j = 0; j < NF; ++j) {
            const int gi = neighIdx[(rowbase + r) * NF + j];    // scalar load
            const float4 v = *(const float4*)(feat + (size_t)gi * DIM + lane * 4);
            a.x += v.x; a.y += v.y; a.z += v.z; a.w += v.w;
        }
        a.x *= sc; a.y *= sc; a.z *= sc; a.w *= sc;
        *(float4*)(&sh_agg[r][lane * 4]) = a;
    }
}

// ---------------- Kernel 1: layer-0 for BOTH hops.
// Blocks [0, 128): hop 0   (self=sn0, neigh=sn1, fanout 10) -> n0 (= d_out scratch)
// Blocks [128,1408): hop 1 (self=sn1, neigh=sn2, fanout 25) -> n1 (= d_ws)
__global__ __launch_bounds__(256) void sage_layer0(
    const float* __restrict__ feat,
    const int*   __restrict__ sn0,
    const int*   __restrict__ sn1,
    const int*   __restrict__ sn2,
    const float* __restrict__ Ws,
    const float* __restrict__ Wn,
    float*       __restrict__ n0,
    float*       __restrict__ n1)
{
    __shared__ float sh_self[R][PAD];
    __shared__ float sh_agg [R][PAD];

    const int tid = threadIdx.x;
    int gb = blockIdx.x;

    float* dst; int rowbase;
    if (gb < B0 / R) {
        rowbase = gb * R;
        dst = n0;
        layer0_gather<F0>(feat, sn0, sn1, rowbase, sh_self, sh_agg);
    } else {
        gb -= B0 / R;
        rowbase = gb * R;
        dst = n1;
        layer0_gather<F1>(feat, sn1, sn2, rowbase, sh_self, sh_agg);
    }
    __syncthreads();

    // ---- phase 2: dual GEMM + ReLU. thread -> 2 adjacent cols x 4 rows.
    const int  u     = tid & 127;
    const int  c0    = u * 2;
    const int  rb    = (tid >> 7) * 4;   // rows 0-3 or 4-7
    const bool neigh = (c0 >= HALF);
    const float* __restrict__ W = neigh ? Wn : Ws;
    const int  col   = neigh ? (c0 - HALF) : c0;
    const float (*src)[PAD] = neigh ? sh_agg : sh_self;

    float acc0[4] = {0.f, 0.f, 0.f, 0.f};
    float acc1[4] = {0.f, 0.f, 0.f, 0.f};

    for (int d = 0; d < DIM; d += 4) {
        const float2 w0 = *(const float2*)(W + (d + 0) * HALF + col);
        const float2 w1 = *(const float2*)(W + (d + 1) * HALF + col);
        const float2 w2 = *(const float2*)(W + (d + 2) * HALF + col);
        const float2 w3 = *(const float2*)(W + (d + 3) * HALF + col);
        #pragma unroll
        for (int r = 0; r < 4; ++r) {
            const float4 h = *(const float4*)(&src[rb + r][d]);  // LDS broadcast
            acc0[r] += h.x * w0.x + h.y * w1.x + h.z * w2.x + h.w * w3.x;
            acc1[r] += h.x * w0.y + h.y * w1.y + h.z * w2.y + h.w * w3.y;
        }
    }

    #pragma unroll
    for (int r = 0; r < 4; ++r) {
        float2 o;
        o.x = fmaxf(acc0[r], 0.f);
        o.y = fmaxf(acc1[r], 0.f);
        *(float2*)(dst + (size_t)(rowbase + rb + r) * DIM + c0) = o;
    }
}

// ---------------- Kernel 2: final layer. out = concat(n0 @ W1s, mean10(n1) @ W1n).
// n0 lives in the out buffer (read rows == written rows, read-before-write per block).
#define R2 4

__global__ __launch_bounds__(256) void sage_final(
    const float* __restrict__ n1,
    const float* __restrict__ W1s,
    const float* __restrict__ W1n,
    float*       out)              // aliases n0 input — no restrict
{
    __shared__ float sh_n0 [R2][PAD];
    __shared__ float sh_agg[R2][PAD];

    const int tid     = threadIdx.x;
    const int rowbase = blockIdx.x * R2;
    const int wave    = tid >> 6;   // wave w -> row w
    const int lane    = tid & 63;

    // ---- phase A: load n0 row; mean of 10 CONSECUTIVE n1 rows (coalesced stream).
    {
        const int r = wave;
        *(float4*)(&sh_n0[r][lane * 4]) =
            *(const float4*)(out + (size_t)(rowbase + r) * DIM + lane * 4);

        const float* base = n1 + (size_t)(rowbase + r) * F0 * DIM + lane * 4;
        float4 a = make_float4(0.f, 0.f, 0.f, 0.f);
        #pragma unroll
        for (int j = 0; j < F0; ++j) {
            const float4 v = *(const float4*)(base + (size_t)j * DIM);
            a.x += v.x; a.y += v.y; a.z += v.z; a.w += v.w;
        }
        const float sc = 1.0f / (float)F0;
        a.x *= sc; a.y *= sc; a.z *= sc; a.w *= sc;
        *(float4*)(&sh_agg[r][lane * 4]) = a;
    }
    __syncthreads();

    // ---- phase B: final GEMM, no activation. thread -> 2 cols x 2 rows.
    const int  u     = tid & 127;
    const int  c0    = u * 2;
    const int  rb    = (tid >> 7) * 2;
    const bool neigh = (c0 >= HALF);
    const float* __restrict__ W = neigh ? W1n : W1s;
    const int  col   = neigh ? (c0 - HALF) : c0;
    const float (*src)[PAD] = neigh ? sh_agg : sh_n0;

    float a0[2] = {0.f, 0.f}, a1[2] = {0.f, 0.f};
    for (int d = 0; d < DIM; d += 4) {
        const float2 w0 = *(const float2*)(W + (d + 0) * HALF + col);
        const float2 w1 = *(const float2*)(W + (d + 1) * HALF + col);
        const float2 w2 = *(const float2*)(W + (d + 2) * HALF + col);
        const float2 w3 = *(const float2*)(W + (d + 3) * HALF + col);
        #pragma unroll
        for (int r = 0; r < 2; ++r) {
            const float4 h = *(const float4*)(&src[rb + r][d]);
            a0[r] += h.x * w0.x + h.y * w1.x + h.z * w2.x + h.w * w3.x;
            a1[r] += h.x * w0.y + h.y * w1.y + h.z * w2.y + h.w * w3.y;
        }
    }

    #pragma unroll
    for (int r = 0; r < 2; ++r) {
        float2 o;
        o.x = a0[r];
        o.y = a1[r];
        *(float2*)(out + (size_t)(rowbase + rb + r) * DIM + c0) = o;
    }
}

extern "C" void kernel_launch(void* const* d_in, const int* in_sizes, int n_in,
                              void* d_out, int out_size, void* d_ws, size_t ws_size,
                              hipStream_t stream) {
    (void)in_sizes; (void)n_in; (void)out_size; (void)ws_size;
    const float* feat = (const float*)d_in[0];
    const int*   sn0  = (const int*)  d_in[1];
    const int*   sn1  = (const int*)  d_in[2];
    const int*   sn2  = (const int*)  d_in[3];
    const float* W0s  = (const float*)d_in[4];
    const float* W0n  = (const float*)d_in[5];
    const float* W1s  = (const float*)d_in[6];
    const float* W1n  = (const float*)d_in[7];
    float* out = (float*)d_out;
    float* n1  = (float*)d_ws;   // 10240*256*4 = 10.49 MB

    // n0 (1024x256) is staged in the out buffer, then overwritten by sage_final.
    sage_layer0<<<(B0 + M1) / R, 256, 0, stream>>>(feat, sn0, sn1, sn2, W0s, W0n, out, n1);
    sage_final <<<B0 / R2, 256, 0, stream>>>(n1, W1s, W1n, out);
}

// Round 4
// 191.738 us; speedup vs baseline: 1.2150x; 1.1868x over previous
//
#include <hip/hip_runtime.h>

#define DIM   256
#define HALF  128
#define F0    10
#define F1    25
#define B0    1024
#define M1    10240   // B0 * F0

typedef __attribute__((ext_vector_type(8))) short     bf16x8;  // 8 bf16 = 4 VGPRs
typedef __attribute__((ext_vector_type(4))) float     f32x4;

#define LSTRIDE 264   // LDS row stride in bf16 elems: 256 + 8 pad (528 B, 16B-aligned)

__device__ __forceinline__ unsigned short f2bf(float x) {
    union { float f; unsigned u; } v; v.f = x;
    unsigned r = v.u + 0x7fffu + ((v.u >> 16) & 1u);   // RNE
    return (unsigned short)(r >> 16);
}
__device__ __forceinline__ float bf2f(unsigned short b) {
    union { unsigned u; float f; } v; v.u = ((unsigned)b) << 16;
    return v.f;
}

// ---------- Prep: W0_{self,neigh} -> bf16 B-fragments in frag-linear order.
// B-frag for (tile t, kstep kk), lane = q*16+n, j=0..7 : W[kk*32+q*8+j][t*16+n]
// stored at bfrag[((mat*64 + t*8+kk)*64 + lane)*8 + j].
__global__ __launch_bounds__(64) void prep_w(
    const float* __restrict__ Ws,
    const float* __restrict__ Wn,
    unsigned short* __restrict__ bfrag)
{
    const int bx   = blockIdx.x;       // [0,128)
    const int mat  = bx >> 6;
    const int f    = bx & 63;          // t*8+kk
    const int t    = f >> 3, kk = f & 7;
    const int lane = threadIdx.x;
    const int n    = lane & 15, q = lane >> 4;
    const float* W = mat ? Wn : Ws;

    __align__(16) unsigned short tmp[8];
    #pragma unroll
    for (int j = 0; j < 8; ++j)
        tmp[j] = f2bf(W[(kk * 32 + q * 8 + j) * HALF + t * 16 + n]);
    *(uint4*)(bfrag + ((size_t)(mat * 64 + f) * 64 + lane) * 8) = *(const uint4*)tmp;
}

// ---------- Layer-0 (both hops): gather + mean -> LDS bf16 -> MFMA dual GEMM + ReLU.
// hop0 (64 blocks):  self=sn0, neigh=sn1, NF=10, dst=n0 fp32 (d_out scratch)
// hop1 (640 blocks): self=sn1, neigh=sn2, NF=25, dst=n1 bf16 (ws)
template<int NF>
__device__ __forceinline__ void layer0_gather(
    const float* __restrict__ feat,
    const int*   __restrict__ selfIdx,
    const int*   __restrict__ neighIdx,
    int rowbase,
    unsigned short (*sh)[16][LSTRIDE])
{
    const int tid  = threadIdx.x;
    const int wv   = __builtin_amdgcn_readfirstlane(tid >> 6);  // 0..7
    const int lane = tid & 63;
    const float sc = 1.0f / (float)NF;

    #pragma unroll
    for (int rr = 0; rr < 2; ++rr) {
        const int r  = wv * 2 + rr;
        const int si = selfIdx[rowbase + r];
        const float4 sv = *(const float4*)(feat + (size_t)si * DIM + lane * 4);
        unsigned short s4[4] = { f2bf(sv.x), f2bf(sv.y), f2bf(sv.z), f2bf(sv.w) };
        *(uint2*)(&sh[0][r][lane * 4]) = *(const uint2*)s4;

        float4 a = make_float4(0.f, 0.f, 0.f, 0.f);
        #pragma unroll
        for (int j = 0; j < NF; ++j) {
            const int gi = neighIdx[(rowbase + r) * NF + j];
            const float4 v = *(const float4*)(feat + (size_t)gi * DIM + lane * 4);
            a.x += v.x; a.y += v.y; a.z += v.z; a.w += v.w;
        }
        unsigned short a4[4] = { f2bf(a.x * sc), f2bf(a.y * sc), f2bf(a.z * sc), f2bf(a.w * sc) };
        *(uint2*)(&sh[1][r][lane * 4]) = *(const uint2*)a4;
    }
}

__global__ __launch_bounds__(512, 4) void sage_layer0(
    const float* __restrict__ feat,
    const int*   __restrict__ sn0,
    const int*   __restrict__ sn1,
    const int*   __restrict__ sn2,
    const unsigned short* __restrict__ bfrag,
    float*          __restrict__ n0,
    unsigned short* __restrict__ n1)
{
    __shared__ __align__(16) unsigned short sh[2][16][LSTRIDE];  // [self|agg][row][dim]

    const int tid = threadIdx.x;
    int gb = blockIdx.x;
    const bool hop0 = (gb < B0 / 16);
    int rowbase;
    if (hop0) {
        rowbase = gb * 16;
        layer0_gather<F0>(feat, sn0, sn1, rowbase, sh);
    } else {
        gb -= B0 / 16;
        rowbase = gb * 16;
        layer0_gather<F1>(feat, sn1, sn2, rowbase, sh);
    }
    __syncthreads();

    // ---- MFMA phase: wave wv -> half h = wv>>2 (0=self,1=agg/neigh), tiles t0 = (wv&3)*2, t0+1.
    const int wv   = __builtin_amdgcn_readfirstlane(tid >> 6);
    const int lane = tid & 63;
    const int h    = wv >> 2;
    const int t0   = (wv & 3) * 2;
    const int m    = lane & 15;        // A row / D col index
    const int q    = lane >> 4;        // quad

    f32x4 acc0 = {0.f, 0.f, 0.f, 0.f};
    f32x4 acc1 = {0.f, 0.f, 0.f, 0.f};

    #pragma unroll
    for (int kk = 0; kk < 8; ++kk) {
        const bf16x8 af = *(const bf16x8*)(&sh[h][m][kk * 32 + q * 8]);
        const bf16x8 b0 = *(const bf16x8*)(bfrag + ((size_t)(h * 64 + (t0 + 0) * 8 + kk) * 64 + lane) * 8);
        const bf16x8 b1 = *(const bf16x8*)(bfrag + ((size_t)(h * 64 + (t0 + 1) * 8 + kk) * 64 + lane) * 8);
        acc0 = __builtin_amdgcn_mfma_f32_16x16x32_bf16(af, b0, acc0, 0, 0, 0);
        acc1 = __builtin_amdgcn_mfma_f32_16x16x32_bf16(af, b1, acc1, 0, 0, 0);
    }

    // ---- epilogue: C/D layout col = lane&15, row = q*4 + reg. ReLU both hops.
    #pragma unroll
    for (int reg = 0; reg < 4; ++reg) {
        const int row  = rowbase + q * 4 + reg;
        const int col0 = h * HALF + (t0 + 0) * 16 + m;
        const int col1 = h * HALF + (t0 + 1) * 16 + m;
        const float v0 = fmaxf(acc0[reg], 0.f);
        const float v1 = fmaxf(acc1[reg], 0.f);
        if (hop0) {
            n0[(size_t)row * DIM + col0] = v0;
            n0[(size_t)row * DIM + col1] = v1;
        } else {
            n1[(size_t)row * DIM + col0] = f2bf(v0);
            n1[(size_t)row * DIM + col1] = f2bf(v1);
        }
    }
}

// ---------- Final layer: out = concat(n0 @ W1s, mean10(n1) @ W1n), fp32 VALU.
#define PAD 260
#define R2  4

__global__ __launch_bounds__(256) void sage_final(
    const unsigned short* __restrict__ n1,
    const float* __restrict__ W1s,
    const float* __restrict__ W1n,
    float*       out)              // aliases n0 input — no restrict
{
    __shared__ float sh_n0 [R2][PAD];
    __shared__ float sh_agg[R2][PAD];

    const int tid     = threadIdx.x;
    const int rowbase = blockIdx.x * R2;
    const int wave    = tid >> 6;
    const int lane    = tid & 63;

    {
        const int r = wave;
        *(float4*)(&sh_n0[r][lane * 4]) =
            *(const float4*)(out + (size_t)(rowbase + r) * DIM + lane * 4);

        const unsigned short* base = n1 + ((size_t)(rowbase + r) * F0) * DIM + lane * 4;
        float4 a = make_float4(0.f, 0.f, 0.f, 0.f);
        #pragma unroll
        for (int j = 0; j < F0; ++j) {
            const uint2 p = *(const uint2*)(base + (size_t)j * DIM);
            a.x += bf2f((unsigned short)(p.x & 0xffff));
            a.y += bf2f((unsigned short)(p.x >> 16));
            a.z += bf2f((unsigned short)(p.y & 0xffff));
            a.w += bf2f((unsigned short)(p.y >> 16));
        }
        const float sc = 1.0f / (float)F0;
        a.x *= sc; a.y *= sc; a.z *= sc; a.w *= sc;
        *(float4*)(&sh_agg[r][lane * 4]) = a;
    }
    __syncthreads();

    const int  u     = tid & 127;
    const int  c0    = u * 2;
    const int  rb    = (tid >> 7) * 2;
    const bool neigh = (c0 >= HALF);
    const float* __restrict__ W = neigh ? W1n : W1s;
    const int  col   = neigh ? (c0 - HALF) : c0;
    const float (*src)[PAD] = neigh ? sh_agg : sh_n0;

    float a0[2] = {0.f, 0.f}, a1[2] = {0.f, 0.f};
    for (int d = 0; d < DIM; d += 4) {
        const float2 w0 = *(const float2*)(W + (d + 0) * HALF + col);
        const float2 w1 = *(const float2*)(W + (d + 1) * HALF + col);
        const float2 w2 = *(const float2*)(W + (d + 2) * HALF + col);
        const float2 w3 = *(const float2*)(W + (d + 3) * HALF + col);
        #pragma unroll
        for (int r = 0; r < 2; ++r) {
            const float4 hh = *(const float4*)(&src[rb + r][d]);
            a0[r] += hh.x * w0.x + hh.y * w1.x + hh.z * w2.x + hh.w * w3.x;
            a1[r] += hh.x * w0.y + hh.y * w1.y + hh.z * w2.y + hh.w * w3.y;
        }
    }

    #pragma unroll
    for (int r = 0; r < 2; ++r) {
        float2 o;
        o.x = a0[r];
        o.y = a1[r];
        *(float2*)(out + (size_t)(rowbase + rb + r) * DIM + c0) = o;
    }
}

extern "C" void kernel_launch(void* const* d_in, const int* in_sizes, int n_in,
                              void* d_out, int out_size, void* d_ws, size_t ws_size,
                              hipStream_t stream) {
    (void)in_sizes; (void)n_in; (void)out_size; (void)ws_size;
    const float* feat = (const float*)d_in[0];
    const int*   sn0  = (const int*)  d_in[1];
    const int*   sn1  = (const int*)  d_in[2];
    const int*   sn2  = (const int*)  d_in[3];
    const float* W0s  = (const float*)d_in[4];
    const float* W0n  = (const float*)d_in[5];
    const float* W1s  = (const float*)d_in[6];
    const float* W1n  = (const float*)d_in[7];
    float* out = (float*)d_out;

    // ws layout: [0, 5.25 MB) n1 bf16 ; then 128 KB of W0 B-fragments (16B-aligned).
    unsigned short* n1    = (unsigned short*)d_ws;                       // 10240*256*2 = 5,242,880 B
    unsigned short* bfrag = (unsigned short*)((char*)d_ws + (size_t)M1 * DIM * 2);

    prep_w<<<128, 64, 0, stream>>>(W0s, W0n, bfrag);
    // n0 (1024x256 fp32) staged in d_out, then overwritten in-place by sage_final.
    sage_layer0<<<(B0 + M1) / 16, 512, 0, stream>>>(feat, sn0, sn1, sn2, bfrag, out, n1);
    sage_final<<<B0 / R2, 256, 0, stream>>>(n1, W1s, W1n, out);
}